// Round 8
// baseline (1309.616 us; speedup 1.0000x reference)
//
#include <hip/hip_runtime.h>
#include <cmath>

#define B_ 2
#define S_ 512
#define D_ 1024
#define H_ 16
#define HD 64
#define M_ 8192
#define HDIM 1024
#define SCALE 0.125f
#define CPL 3      // candidates per lane; 16 lanes/query -> top-48 screen

using bf16x8 = __attribute__((ext_vector_type(8))) short;
using f32x4  = __attribute__((ext_vector_type(4))) float;

// pack two f32 (hi,lo) -> one u32 holding [bf16(lo) | bf16(hi)<<16] (truncation)
__device__ inline unsigned pkbf(unsigned hi, unsigned lo) {
    return __builtin_amdgcn_perm(hi, lo, 0x07060302u);
}

// DPP lane moves (full-rate VALU). Controls: 0x140=row_mirror (i^15 within 16),
// 0x141=row_half_mirror (i^7), 0x4E=quad_perm xor2, 0xB1=quad_perm xor1,
// 0x111=row_shr:1. {15,7,2,1} generate all of Z2^4 -> 4-step 16-lane butterfly.
template<int CTRL>
__device__ inline int dppmov(int x) {
    return __builtin_amdgcn_update_dpp(0, x, CTRL, 0xF, 0xF, true);
}
template<int CTRL>
__device__ inline float dppmovf(float x) {
    return __int_as_float(__builtin_amdgcn_update_dpp(0, __float_as_int(x), CTRL, 0xF, 0xF, true));
}

// ---------------- K1: QKV projection GEMM (64x64 tile, f32) ----------------
__global__ __launch_bounds__(256) void qkv_gemm(
    const float* __restrict__ A,
    const float* __restrict__ Wq, const float* __restrict__ bq,
    const float* __restrict__ Wk, const float* __restrict__ bk,
    const float* __restrict__ Wv, const float* __restrict__ bv,
    float* __restrict__ qo, float* __restrict__ ko, float* __restrict__ vo)
{
    const int which = blockIdx.z;
    const float* W    = (which==0)?Wq:((which==1)?Wk:Wv);
    const float* bias = (which==0)?bq:((which==1)?bk:bv);
    float* out        = (which==0)?qo:((which==1)?ko:vo);
    const int rb = blockIdx.y*64, cb = blockIdx.x*64;
    __shared__ float As[16][68];
    __shared__ float Bs[16][68];
    const int tid = threadIdx.x;
    const int ty = tid>>4, tx = tid&15;
    const int ar = tid>>2, ac4 = (tid&3)<<2;
    const int bkr = tid>>4, bc4 = (tid&15)<<2;
    float acc[4][4] = {};
    for (int kb=0; kb<D_; kb+=16) {
        float4 av  = *(const float4*)&A[(size_t)(rb+ar)*D_ + kb + ac4];
        float4 bvv = *(const float4*)&W[(size_t)(kb+bkr)*HDIM + cb + bc4];
        __syncthreads();
        As[ac4+0][ar]=av.x; As[ac4+1][ar]=av.y; As[ac4+2][ar]=av.z; As[ac4+3][ar]=av.w;
        *(float4*)&Bs[bkr][bc4] = bvv;
        __syncthreads();
        #pragma unroll
        for (int kk=0; kk<16; kk++) {
            float a[4], b[4];
            *(float4*)a = *(const float4*)&As[kk][ty<<2];
            *(float4*)b = *(const float4*)&Bs[kk][tx<<2];
            #pragma unroll
            for (int i=0;i<4;i++)
                #pragma unroll
                for (int j=0;j<4;j++) acc[i][j] += a[i]*b[j];
        }
    }
    const int c0 = cb + (tx<<2);
    float4 bb = *(const float4*)&bias[c0];
    const int h = c0>>6, dd = c0&63;
    #pragma unroll
    for (int i=0;i<4;i++) {
        int n = rb + (ty<<2) + i;
        int b = n>>9, s = n&511;
        float4 r;
        r.x = acc[i][0]+bb.x; r.y = acc[i][1]+bb.y;
        r.z = acc[i][2]+bb.z; r.w = acc[i][3]+bb.w;
        *(float4*)&out[((size_t)(b*H_+h)*S_ + s)*HD + dd] = r;
    }
}

// ---------------- K6: output projection GEMM ----------------
__global__ __launch_bounds__(256) void out_gemm(
    const float* __restrict__ A, const float* __restrict__ W, float* __restrict__ out)
{
    const int rb = blockIdx.y*64, cb = blockIdx.x*64;
    __shared__ float As[16][68];
    __shared__ float Bs[16][68];
    const int tid = threadIdx.x;
    const int ty = tid>>4, tx = tid&15;
    const int ar = tid>>2, ac4 = (tid&3)<<2;
    const int bkr = tid>>4, bc4 = (tid&15)<<2;
    float acc[4][4] = {};
    for (int kb=0; kb<HDIM; kb+=16) {
        float4 av  = *(const float4*)&A[(size_t)(rb+ar)*HDIM + kb + ac4];
        float4 bvv = *(const float4*)&W[(size_t)(kb+bkr)*D_ + cb + bc4];
        __syncthreads();
        As[ac4+0][ar]=av.x; As[ac4+1][ar]=av.y; As[ac4+2][ar]=av.z; As[ac4+3][ar]=av.w;
        *(float4*)&Bs[bkr][bc4] = bvv;
        __syncthreads();
        #pragma unroll
        for (int kk=0; kk<16; kk++) {
            float a[4], b[4];
            *(float4*)a = *(const float4*)&As[kk][ty<<2];
            *(float4*)b = *(const float4*)&Bs[kk][tx<<2];
            #pragma unroll
            for (int i=0;i<4;i++)
                #pragma unroll
                for (int j=0;j<4;j++) acc[i][j] += a[i]*b[j];
        }
    }
    const int c0 = cb + (tx<<2);
    #pragma unroll
    for (int i=0;i<4;i++) {
        int n = rb + (ty<<2) + i;
        float4 r;
        r.x=acc[i][0]; r.y=acc[i][1]; r.z=acc[i][2]; r.w=acc[i][3];
        *(float4*)&out[(size_t)n*D_ + c0] = r;
    }
}

// ---------------- K2: RoPE in-place on q,k ----------------
__global__ __launch_bounds__(256) void rope_kernel(
    float* __restrict__ q, float* __restrict__ k,
    const float* __restrict__ cosb, const float* __restrict__ sinb)
{
    int t = blockIdx.x*256 + threadIdx.x;
    int pair = t & 31;
    int s    = (t>>5) & 511;
    int bh   = (t>>14) & 31;
    float* x = (t>>19) ? k : q;
    float* xb = x + ((size_t)(bh*S_ + s))*HD;
    float c  = cosb[s*HD + pair];
    float sn = sinb[s*HD + pair];
    float x1 = xb[pair], x2 = xb[pair+32];
    xb[pair]    = x1*c - x2*sn;
    xb[pair+32] = x2*c + x1*sn;
}

// ---------------- K3: wave-private MFMA sim + register top-48 screen -------
// 128 thr (2 waves) per block; wave owns 16 queries x all M. D[q][m] layout:
// query q = 4*(lane>>4)+reg lives in one 16-lane DPP row (cohort = lane>>4);
// m-col = lane&15. Selection entirely in registers via 4-step DPP butterflies
// (xor15/7/2/1). NO barriers in the main loop; one barrier total (q staging).
// Exact f32 rescore of the 48 candidates, then exact top-32.
__global__ __launch_bounds__(128) void sim_topk_wave(
    const float* __restrict__ q, const float* __restrict__ memk,
    float* __restrict__ topV, int* __restrict__ topI)
{
    __shared__ __align__(16) float qs[32][64];   // 8KB: q f32 (frags + rescore)
    const int tid = threadIdx.x;
    // XCD-aware swizzle (bijective: 512 blocks, id&7 -> XCD)
    int id = blockIdx.x;                          // 0..511
    int virt = (id & 7)*64 + (id >> 3);
    const int bh = virt >> 4, qt = virt & 15;     // 32 bh x 16 q-tiles of 32
    const float* qbase = q + ((size_t)bh*S_ + qt*32)*HD;
    const float* kbase = memk + (size_t)bh*M_*HD;

    for (int i = tid; i < 32*16; i += 128) {      // stage q f32 (32x64)
        int r = i >> 4, c = (i & 15) << 2;
        *(f32x4*)&qs[r][c] = *(const f32x4*)&qbase[(size_t)r*HD + c];
    }
    __syncthreads();

    const int lane = tid & 63;
    const int w  = tid >> 6;                  // wave 0..1 -> 16-query slice
    const int fr = lane & 15, fc = lane >> 4;

    // A-frags: q rows (this wave's 16 queries), truncated to bf16.
    // A[l&15][kc*32 + 8*(l>>4)+j]
    bf16x8 a[2];
    #pragma unroll
    for (int kc = 0; kc < 2; kc++) {
        const float* p = &qs[w*16 + fr][kc*32 + 8*fc];
        union { bf16x8 v; unsigned u[4]; } u;
        #pragma unroll
        for (int jj = 0; jj < 4; jj++)
            u.u[jj] = pkbf(__float_as_uint(p[2*jj+1]), __float_as_uint(p[2*jj]));
        a[kc] = u.v;
    }

    // candidate lists: query (4*fc + r) rank = fr*CPL + slot, desc by score
    float ckey[4][CPL]; int cidx[4][CPL]; float rminf[4];
    #pragma unroll
    for (int r = 0; r < 4; r++) {
        rminf[r] = -INFINITY;
        #pragma unroll
        for (int s = 0; s < CPL; s++) { ckey[r][s] = -INFINITY; cidx[r][s] = 0; }
    }

    // B staging: batch = 64 m (4 subtiles of 16). Lane loads memk row
    // (m0+16s+fr), k-chunk kc*32+8*fc (+4). pf[s][2*kc+half].
    f32x4 pf[4][4];
    #pragma unroll
    for (int s = 0; s < 4; s++) {
        const float* p = &kbase[(size_t)(16*s + fr)*HD + 8*fc];
        pf[s][0] = *(const f32x4*)p;      pf[s][1] = *(const f32x4*)(p+4);
        pf[s][2] = *(const f32x4*)(p+32); pf[s][3] = *(const f32x4*)(p+36);
    }

    for (int t = 0; t < 128; t++) {
        const int m0 = t << 6;
        // convert staged f32 -> bf16 B-frags
        bf16x8 bfr[4][2];
        #pragma unroll
        for (int s = 0; s < 4; s++)
            #pragma unroll
            for (int kc = 0; kc < 2; kc++) {
                union { bf16x8 v; unsigned u[4]; } u;
                f32x4 lo4 = pf[s][2*kc], hi4 = pf[s][2*kc+1];
                u.u[0] = pkbf(__float_as_uint(lo4.y), __float_as_uint(lo4.x));
                u.u[1] = pkbf(__float_as_uint(lo4.w), __float_as_uint(lo4.z));
                u.u[2] = pkbf(__float_as_uint(hi4.y), __float_as_uint(hi4.x));
                u.u[3] = pkbf(__float_as_uint(hi4.w), __float_as_uint(hi4.z));
                bfr[s][kc] = u.v;
            }
        // issue next-batch loads (wraps harmlessly on last)
        {
            const int mn = ((t+1) & 127) << 6;
            #pragma unroll
            for (int s = 0; s < 4; s++) {
                const float* p = &kbase[(size_t)(mn + 16*s + fr)*HD + 8*fc];
                pf[s][0] = *(const f32x4*)p;      pf[s][1] = *(const f32x4*)(p+4);
                pf[s][2] = *(const f32x4*)(p+32); pf[s][3] = *(const f32x4*)(p+36);
            }
        }
        // MFMAs: D[s] = q . memk^T for m-subtile s
        f32x4 D0, D1, D2, D3;
        {
            f32x4 z = (f32x4){0.f,0.f,0.f,0.f};
            D0 = __builtin_amdgcn_mfma_f32_16x16x32_bf16(a[0], bfr[0][0], z, 0,0,0);
            D0 = __builtin_amdgcn_mfma_f32_16x16x32_bf16(a[1], bfr[0][1], D0, 0,0,0);
            D1 = __builtin_amdgcn_mfma_f32_16x16x32_bf16(a[0], bfr[1][0], z, 0,0,0);
            D1 = __builtin_amdgcn_mfma_f32_16x16x32_bf16(a[1], bfr[1][1], D1, 0,0,0);
            D2 = __builtin_amdgcn_mfma_f32_16x16x32_bf16(a[0], bfr[2][0], z, 0,0,0);
            D2 = __builtin_amdgcn_mfma_f32_16x16x32_bf16(a[1], bfr[2][1], D2, 0,0,0);
            D3 = __builtin_amdgcn_mfma_f32_16x16x32_bf16(a[0], bfr[3][0], z, 0,0,0);
            D3 = __builtin_amdgcn_mfma_f32_16x16x32_bf16(a[1], bfr[3][1], D3, 0,0,0);
        }
        // probe + extract per query-reg r (serial over 4, concurrent over rows)
        #pragma unroll
        for (int r = 0; r < 4; r++) {
            float bmax = fmaxf(fmaxf(D0[r], D1[r]), fmaxf(D2[r], D3[r]));
            bmax = fmaxf(bmax, dppmovf<0x140>(bmax));
            bmax = fmaxf(bmax, dppmovf<0x141>(bmax));
            bmax = fmaxf(bmax, dppmovf<0x4E>(bmax));
            bmax = fmaxf(bmax, dppmovf<0xB1>(bmax));
            if (bmax <= rminf[r]) continue;
            while (true) {
                float lv = D0[r]; int ls = 0;
                if (D1[r] > lv) { lv = D1[r]; ls = 1; }
                if (D2[r] > lv) { lv = D2[r]; ls = 2; }
                if (D3[r] > lv) { lv = D3[r]; ls = 3; }
                float gv = lv; int gc = (fr << 2) | ls;
                { float ov=dppmovf<0x140>(gv); int oc=dppmov<0x140>(gc);
                  if (ov>gv || (ov==gv && oc<gc)) { gv=ov; gc=oc; } }
                { float ov=dppmovf<0x141>(gv); int oc=dppmov<0x141>(gc);
                  if (ov>gv || (ov==gv && oc<gc)) { gv=ov; gc=oc; } }
                { float ov=dppmovf<0x4E>(gv);  int oc=dppmov<0x4E>(gc);
                  if (ov>gv || (ov==gv && oc<gc)) { gv=ov; gc=oc; } }
                { float ov=dppmovf<0xB1>(gv);  int oc=dppmov<0xB1>(gc);
                  if (ov>gv || (ov==gv && oc<gc)) { gv=ov; gc=oc; } }
                if (gv <= rminf[r]) break;
                if ((gc >> 2) == fr) {           // winner clears its score
                    int ls2 = gc & 3;
                    if (ls2 == 0) D0[r] = -INFINITY;
                    else if (ls2 == 1) D1[r] = -INFINITY;
                    else if (ls2 == 2) D2[r] = -INFINITY;
                    else D3[r] = -INFINITY;
                }
                int gidx = m0 + ((gc & 3) << 4) + (gc >> 2);
                // sorted-desc insert; prev rank via DPP row_shr:1
                float pk = dppmovf<0x111>(ckey[r][CPL-1]);
                int   pj = dppmov<0x111>(cidx[r][CPL-1]);
                float pv = (fr == 0) ? INFINITY : pk;
                int   pi = (fr == 0) ? 0 : pj;
                float o0 = ckey[r][0], o1 = ckey[r][1], o2 = ckey[r][2];
                int   i0 = cidx[r][0], i1 = cidx[r][1], i2 = cidx[r][2];
                { bool gcb = o0 > gv, gp = pv > gv;
                  ckey[r][0] = gcb ? o0 : (gp ? gv : pv);
                  cidx[r][0] = gcb ? i0 : (gp ? gidx : pi); }
                { bool gcb = o1 > gv, gp = o0 > gv;
                  ckey[r][1] = gcb ? o1 : (gp ? gv : o0);
                  cidx[r][1] = gcb ? i1 : (gp ? gidx : i0); }
                { bool gcb = o2 > gv, gp = o1 > gv;
                  ckey[r][2] = gcb ? o2 : (gp ? gv : o1);
                  cidx[r][2] = gcb ? i2 : (gp ? gidx : i1); }
                float rm = ckey[r][CPL-1];
                rm = fminf(rm, dppmovf<0x140>(rm));
                rm = fminf(rm, dppmovf<0x141>(rm));
                rm = fminf(rm, dppmovf<0x4E>(rm));
                rm = fminf(rm, dppmovf<0xB1>(rm));
                rminf[r] = rm;
            }
        }
    }

    // ---- exact f32 rescore of the 48 candidates per query ----
    float rsv[4][CPL];
    #pragma unroll
    for (int r = 0; r < 4; r++) {
        const float* qrow = &qs[w*16 + 4*fc + r][0];
        #pragma unroll
        for (int s = 0; s < CPL; s++) {
            const float* kr = &kbase[(size_t)cidx[r][s] * HD];
            float accr = 0.f;
            #pragma unroll
            for (int j = 0; j < 64; j += 4) {
                f32x4 kv = *(const f32x4*)&kr[j];
                f32x4 qv = *(const f32x4*)&qrow[j];
                accr += qv.x*kv.x + qv.y*kv.y + qv.z*kv.z + qv.w*kv.w;
            }
            rsv[r][s] = accr;
        }
    }
    // ---- exact top-32 of 48 by extract-max (DPP row argmax) ----
    const int qgb = bh*S_ + qt*32;
    #pragma unroll
    for (int r = 0; r < 4; r++) {
        float* tVo = &topV[(size_t)(qgb + w*16 + 4*fc + r)*32];
        int*   tIo = &topI[(size_t)(qgb + w*16 + 4*fc + r)*32];
        #pragma unroll 1
        for (int it = 0; it < 32; it++) {
            float lv = rsv[r][0]; int ls = 0;
            if (rsv[r][1] > lv) { lv = rsv[r][1]; ls = 1; }
            if (rsv[r][2] > lv) { lv = rsv[r][2]; ls = 2; }
            float gv = lv; int gc = (fr << 2) | ls;
            { float ov=dppmovf<0x140>(gv); int oc=dppmov<0x140>(gc);
              if (ov>gv || (ov==gv && oc<gc)) { gv=ov; gc=oc; } }
            { float ov=dppmovf<0x141>(gv); int oc=dppmov<0x141>(gc);
              if (ov>gv || (ov==gv && oc<gc)) { gv=ov; gc=oc; } }
            { float ov=dppmovf<0x4E>(gv);  int oc=dppmov<0x4E>(gc);
              if (ov>gv || (ov==gv && oc<gc)) { gv=ov; gc=oc; } }
            { float ov=dppmovf<0xB1>(gv);  int oc=dppmov<0xB1>(gc);
              if (ov>gv || (ov==gv && oc<gc)) { gv=ov; gc=oc; } }
            if ((gc >> 2) == fr) {
                int ls2 = gc & 3;
                int idx = cidx[r][0];
                if (ls2 == 1) idx = cidx[r][1];
                else if (ls2 == 2) idx = cidx[r][2];
                if (ls2 == 0) rsv[r][0] = -INFINITY;
                else if (ls2 == 1) rsv[r][1] = -INFINITY;
                else rsv[r][2] = -INFINITY;
                tVo[it] = gv; tIo[it] = idx;
            }
        }
    }
}

// ---------------- K5: fused local-causal + memory attention ----------------
__global__ __launch_bounds__(256) void attn_fused(
    const float* __restrict__ q, const float* __restrict__ k, const float* __restrict__ v,
    const float* __restrict__ topV, const int* __restrict__ topI,
    const float* __restrict__ memv, float* __restrict__ attn)
{
    __shared__ float Ks[64][68];
    __shared__ float Vs[64][68];
    __shared__ float Qs[32][68];
    __shared__ float pt[32][68];
    const int tid = threadIdx.x;
    const int qt = blockIdx.x, bh = blockIdx.y;
    const float* qbase = q + ((size_t)bh*S_ + qt*32)*HD;
    {
        int fi = tid; int r = fi>>4, c = (fi&15)<<2;
        float4 t4 = *(const float4*)&qbase[(size_t)r*HD + c];
        t4.x*=SCALE; t4.y*=SCALE; t4.z*=SCALE; t4.w*=SCALE;
        *(float4*)&Qs[r][c] = t4;
        fi = tid+256; r = fi>>4; c = (fi&15)<<2;
        t4 = *(const float4*)&qbase[(size_t)r*HD + c];
        t4.x*=SCALE; t4.y*=SCALE; t4.z*=SCALE; t4.w*=SCALE;
        *(float4*)&Qs[r][c] = t4;
    }
    __syncthreads();
    const int ql = tid>>3, lg = tid&7;
    const int dd0 = lg<<3;
    float qreg[64];
    #pragma unroll
    for (int j=0;j<64;j+=4) *(float4*)&qreg[j] = *(const float4*)&Qs[ql][j];
    const int qpos = qt*32 + ql;
    const size_t qg = (size_t)bh*S_ + qpos;

    float m = -INFINITY, l = 0.f;
    float acc[8] = {0,0,0,0,0,0,0,0};
    const float* tvp = &topV[qg*32];
    const int*   tip = &topI[qg*32];
    #pragma unroll 8
    for (int j=0;j<32;j++) m = fmaxf(m, tvp[j]*SCALE);
    #pragma unroll 4
    for (int j=0;j<32;j++) {
        float p = __expf(tvp[j]*SCALE - m);
        l += p;
        const float* mvr = &memv[((size_t)bh*M_ + tip[j])*HD + dd0];
        float4 a  = *(const float4*)&mvr[0];
        float4 b2 = *(const float4*)&mvr[4];
        acc[0]+=p*a.x;  acc[1]+=p*a.y;  acc[2]+=p*a.z;  acc[3]+=p*a.w;
        acc[4]+=p*b2.x; acc[5]+=p*b2.y; acc[6]+=p*b2.z; acc[7]+=p*b2.w;
    }
    const int ntiles = (qt*32 + 31)/64 + 1;
    const float* kb2 = k + ((size_t)bh*S_)*HD;
    const float* vb2 = v + ((size_t)bh*S_)*HD;
    for (int kt=0; kt<ntiles; kt++) {
        __syncthreads();
        for (int fi=tid; fi<1024; fi+=256) {
            int r = fi>>4, c = (fi&15)<<2;
            *(float4*)&Ks[r][c] = *(const float4*)&kb2[(size_t)(kt*64+r)*HD + c];
            *(float4*)&Vs[r][c] = *(const float4*)&vb2[(size_t)(kt*64+r)*HD + c];
        }
        __syncthreads();
        float s8[8];
        #pragma unroll
        for (int rr=0; rr<8; rr++) {
            int row = lg + (rr<<3);
            float acc2 = 0.f;
            #pragma unroll
            for (int j=0;j<64;j+=4) {
                float4 kv = *(const float4*)&Ks[row][j];
                acc2 += qreg[j]*kv.x + qreg[j+1]*kv.y + qreg[j+2]*kv.z + qreg[j+3]*kv.w;
            }
            int kpos = kt*64 + row;
            s8[rr] = (kpos <= qpos) ? acc2 : -INFINITY;
        }
        float tmax = s8[0];
        #pragma unroll
        for (int rr=1; rr<8; rr++) tmax = fmaxf(tmax, s8[rr]);
        #pragma unroll
        for (int off=1; off<8; off<<=1) tmax = fmaxf(tmax, __shfl_xor(tmax, off));
        float mnew = fmaxf(m, tmax);
        float f = __expf(m - mnew);
        l *= f;
        #pragma unroll
        for (int i=0;i<8;i++) acc[i] *= f;
        float psum = 0.f;
        #pragma unroll
        for (int rr=0; rr<8; rr++) {
            float p = __expf(s8[rr] - mnew);
            psum += p;
            pt[ql][lg + (rr<<3)] = p;
        }
        #pragma unroll
        for (int off=1; off<8; off<<=1) psum += __shfl_xor(psum, off);
        l += psum; m = mnew;
        #pragma unroll 8
        for (int r=0; r<64; r++) {
            float p = pt[ql][r];
            float4 a  = *(const float4*)&Vs[r][dd0];
            float4 b2 = *(const float4*)&Vs[r][dd0+4];
            acc[0]+=p*a.x;  acc[1]+=p*a.y;  acc[2]+=p*a.z;  acc[3]+=p*a.w;
            acc[4]+=p*b2.x; acc[5]+=p*b2.y; acc[6]+=p*b2.z; acc[7]+=p*b2.w;
        }
    }
    float inv = 1.0f / l;
    const int b = bh>>4, h = bh&15;
    float4 o;
    o.x=acc[0]*inv; o.y=acc[1]*inv; o.z=acc[2]*inv; o.w=acc[3]*inv;
    *(float4*)&attn[((size_t)(b*S_)+qpos)*HDIM + h*HD + dd0] = o;
    o.x=acc[4]*inv; o.y=acc[5]*inv; o.z=acc[6]*inv; o.w=acc[7]*inv;
    *(float4*)&attn[((size_t)(b*S_)+qpos)*HDIM + h*HD + dd0 + 4] = o;
}

extern "C" void kernel_launch(void* const* d_in, const int* in_sizes, int n_in,
                              void* d_out, int out_size, void* d_ws, size_t ws_size,
                              hipStream_t stream)
{
    const float* hs   = (const float*)d_in[0];
    const float* cosb = (const float*)d_in[1];
    const float* sinb = (const float*)d_in[2];
    const float* memk = (const float*)d_in[3];
    const float* memv = (const float*)d_in[4];
    const float* Wq = (const float*)d_in[5];
    const float* bq = (const float*)d_in[6];
    const float* Wk = (const float*)d_in[7];
    const float* bk = (const float*)d_in[8];
    const float* Wv = (const float*)d_in[9];
    const float* bv = (const float*)d_in[10];
    const float* Wo = (const float*)d_in[11];
    float* out = (float*)d_out;
    float* ws = (float*)d_ws;
    float* qw = ws;                    // 1M floats
    float* kw = ws + 1048576;          // 1M
    float* vw = ws + 2097152;          // 1M
    float* tV = ws + 3145728;          // 512K
    int*   tI = (int*)(ws + 3670016);  // 512K
    float* ao = ws + 4194304;          // 1M

    qkv_gemm<<<dim3(16,16,3),256,0,stream>>>(hs, Wq,bq,Wk,bk,Wv,bv, qw,kw,vw);
    rope_kernel<<<4096,256,0,stream>>>(qw,kw,cosb,sinb);
    sim_topk_wave<<<512,128,0,stream>>>(qw, memk, tV, tI);
    attn_fused<<<dim3(16,32),256,0,stream>>>(qw,kw,vw, tV,tI, memv, ao);
    out_gemm<<<dim3(16,16),256,0,stream>>>(ao, Wo, out);
}

// Round 9
// 689.934 us; speedup vs baseline: 1.8982x; 1.8982x over previous
//
#include <hip/hip_runtime.h>
#include <cmath>

#define B_ 2
#define S_ 512
#define D_ 1024
#define H_ 16
#define HD 64
#define M_ 8192
#define HDIM 1024
#define SCALE 0.125f
#define NCAND 40   // screened candidates per query (top-32 + 8 margin)
#define CPL 5      // candidates per lane (8 lanes/query)

using bf16x8 = __attribute__((ext_vector_type(8))) short;
using f32x4  = __attribute__((ext_vector_type(4))) float;

// pack two f32 (hi,lo) -> one u32 holding [bf16(lo) | bf16(hi)<<16] (truncation)
__device__ inline unsigned pkbf(unsigned hi, unsigned lo) {
    return __builtin_amdgcn_perm(hi, lo, 0x07060302u);
}
// monotone u16 sort keys for 2 packed bf16 (order-preserving for floats)
__device__ inline unsigned key2(unsigned u) {
    unsigned m = u & 0x80008000u;
    return u ^ (m - (m >> 15)) ^ 0x80008000u;
}

// DPP lane move (full-rate VALU). 0x141=row_half_mirror (i<->7-i within 8),
// 0x4E=quad_perm[2,3,0,1] (xor2), 0xB1=quad_perm[1,0,3,2] (xor1), 0x111=row_shr:1
template<int CTRL>
__device__ inline int dppmov(int x) {
    return __builtin_amdgcn_update_dpp(0, x, CTRL, 0xF, 0xF, true);
}

// ---------------- K1: QKV projection GEMM (64x64 tile, f32) ----------------
__global__ __launch_bounds__(256) void qkv_gemm(
    const float* __restrict__ A,
    const float* __restrict__ Wq, const float* __restrict__ bq,
    const float* __restrict__ Wk, const float* __restrict__ bk,
    const float* __restrict__ Wv, const float* __restrict__ bv,
    float* __restrict__ qo, float* __restrict__ ko, float* __restrict__ vo)
{
    const int which = blockIdx.z;
    const float* W    = (which==0)?Wq:((which==1)?Wk:Wv);
    const float* bias = (which==0)?bq:((which==1)?bk:bv);
    float* out        = (which==0)?qo:((which==1)?ko:vo);
    const int rb = blockIdx.y*64, cb = blockIdx.x*64;
    __shared__ float As[16][68];
    __shared__ float Bs[16][68];
    const int tid = threadIdx.x;
    const int ty = tid>>4, tx = tid&15;
    const int ar = tid>>2, ac4 = (tid&3)<<2;
    const int bkr = tid>>4, bc4 = (tid&15)<<2;
    float acc[4][4] = {};
    for (int kb=0; kb<D_; kb+=16) {
        float4 av  = *(const float4*)&A[(size_t)(rb+ar)*D_ + kb + ac4];
        float4 bvv = *(const float4*)&W[(size_t)(kb+bkr)*HDIM + cb + bc4];
        __syncthreads();
        As[ac4+0][ar]=av.x; As[ac4+1][ar]=av.y; As[ac4+2][ar]=av.z; As[ac4+3][ar]=av.w;
        *(float4*)&Bs[bkr][bc4] = bvv;
        __syncthreads();
        #pragma unroll
        for (int kk=0; kk<16; kk++) {
            float a[4], b[4];
            *(float4*)a = *(const float4*)&As[kk][ty<<2];
            *(float4*)b = *(const float4*)&Bs[kk][tx<<2];
            #pragma unroll
            for (int i=0;i<4;i++)
                #pragma unroll
                for (int j=0;j<4;j++) acc[i][j] += a[i]*b[j];
        }
    }
    const int c0 = cb + (tx<<2);
    float4 bb = *(const float4*)&bias[c0];
    const int h = c0>>6, dd = c0&63;
    #pragma unroll
    for (int i=0;i<4;i++) {
        int n = rb + (ty<<2) + i;
        int b = n>>9, s = n&511;
        float4 r;
        r.x = acc[i][0]+bb.x; r.y = acc[i][1]+bb.y;
        r.z = acc[i][2]+bb.z; r.w = acc[i][3]+bb.w;
        *(float4*)&out[((size_t)(b*H_+h)*S_ + s)*HD + dd] = r;
    }
}

// ---------------- K6: output projection GEMM ----------------
__global__ __launch_bounds__(256) void out_gemm(
    const float* __restrict__ A, const float* __restrict__ W, float* __restrict__ out)
{
    const int rb = blockIdx.y*64, cb = blockIdx.x*64;
    __shared__ float As[16][68];
    __shared__ float Bs[16][68];
    const int tid = threadIdx.x;
    const int ty = tid>>4, tx = tid&15;
    const int ar = tid>>2, ac4 = (tid&3)<<2;
    const int bkr = tid>>4, bc4 = (tid&15)<<2;
    float acc[4][4] = {};
    for (int kb=0; kb<HDIM; kb+=16) {
        float4 av  = *(const float4*)&A[(size_t)(rb+ar)*HDIM + kb + ac4];
        float4 bvv = *(const float4*)&W[(size_t)(kb+bkr)*D_ + cb + bc4];
        __syncthreads();
        As[ac4+0][ar]=av.x; As[ac4+1][ar]=av.y; As[ac4+2][ar]=av.z; As[ac4+3][ar]=av.w;
        *(float4*)&Bs[bkr][bc4] = bvv;
        __syncthreads();
        #pragma unroll
        for (int kk=0; kk<16; kk++) {
            float a[4], b[4];
            *(float4*)a = *(const float4*)&As[kk][ty<<2];
            *(float4*)b = *(const float4*)&Bs[kk][tx<<2];
            #pragma unroll
            for (int i=0;i<4;i++)
                #pragma unroll
                for (int j=0;j<4;j++) acc[i][j] += a[i]*b[j];
        }
    }
    const int c0 = cb + (tx<<2);
    #pragma unroll
    for (int i=0;i<4;i++) {
        int n = rb + (ty<<2) + i;
        float4 r;
        r.x=acc[i][0]; r.y=acc[i][1]; r.z=acc[i][2]; r.w=acc[i][3];
        *(float4*)&out[(size_t)n*D_ + c0] = r;
    }
}

// ---------------- K2: RoPE in-place on q,k ----------------
__global__ __launch_bounds__(256) void rope_kernel(
    float* __restrict__ q, float* __restrict__ k,
    const float* __restrict__ cosb, const float* __restrict__ sinb)
{
    int t = blockIdx.x*256 + threadIdx.x;
    int pair = t & 31;
    int s    = (t>>5) & 511;
    int bh   = (t>>14) & 31;
    float* x = (t>>19) ? k : q;
    float* xb = x + ((size_t)(bh*S_ + s))*HD;
    float c  = cosb[s*HD + pair];
    float sn = sinb[s*HD + pair];
    float x1 = xb[pair], x2 = xb[pair+32];
    xb[pair]    = x1*c - x2*sn;
    xb[pair+32] = x2*c + x1*sn;
}

// ---------------- K3: MFMA sim + register top-40 screen + f32 rescore ------
// 512 thr (8 waves), 64 queries x full M. Merge loop is register-resident:
// per tile each lane loads its 16 bf16 keys once; tree argmax (depth 4) per
// lane; 8-lane DPP butterfly; rmin via DPP min-reduce (no ds_bpermute).
__global__ __launch_bounds__(512) void sim_topk_mfma(
    const float* __restrict__ q, const float* __restrict__ memk,
    float* __restrict__ topV, int* __restrict__ topI)
{
    __shared__ unsigned short sc[64][136];        // bf16 sort-keys per (q, m); 16B-aligned rows
    __shared__ __align__(16) float qs[64][64];    // f32 q tile (for rescore)
    const int tid = threadIdx.x;
    // XCD-aware swizzle: 8 consecutive-on-XCD blocks share one bh panel
    int id = blockIdx.x;                 // 0..255
    int virt = (id & 7)*32 + (id >> 3);
    const int bh = virt >> 3, qt = virt & 7;
    const float* qbase = q + ((size_t)bh*S_ + qt*64)*HD;
    const float* kbase = memk + (size_t)bh*M_*HD;

    for (int i = tid; i < 64*16; i += 512) {      // stage q f32 (64x64)
        int r = i >> 4, c = (i & 15) << 2;
        *(f32x4*)&qs[r][c] = *(const f32x4*)&qbase[(size_t)r*HD + c];
    }
    __syncthreads();

    const int lane = tid & 63;
    const int wv = tid >> 6;                  // wave 0..7 -> m-subtile
    const int fr = lane & 15, fc = lane >> 4; // frag row / k-chunk

    // B-fragments: q[qh*16+fr][32*kc + 8*fc + j], truncated to bf16
    bf16x8 bq[4][2];
    #pragma unroll
    for (int qh = 0; qh < 4; qh++)
        #pragma unroll
        for (int kc = 0; kc < 2; kc++) {
            const float* p = &qs[qh*16 + fr][kc*32 + 8*fc];
            union { bf16x8 v; unsigned u[4]; } u;
            #pragma unroll
            for (int jj = 0; jj < 4; jj++)
                u.u[jj] = pkbf(__float_as_uint(p[2*jj+1]), __float_as_uint(p[2*jj]));
            bq[qh][kc] = u.v;
        }

    const int ql = tid >> 3, lg = tid & 7;
    // register candidate list: group rank = lg*CPL + s (descending keys)
    int ckey[CPL], cidx[CPL];
    #pragma unroll
    for (int s = 0; s < CPL; s++) { ckey[s] = 0; cidx[s] = 0; }
    int rmin = -1;

    f32x4 pf[2][2];
    {   // preload tile 0 A-fragments (f32)
        const float* p = &kbase[(size_t)(wv*16 + fr)*HD + 8*fc];
        pf[0][0] = *(const f32x4*)p;      pf[0][1] = *(const f32x4*)(p+4);
        pf[1][0] = *(const f32x4*)(p+32); pf[1][1] = *(const f32x4*)(p+36);
    }

    for (int mt = 0; mt < M_; mt += 128) {
        // convert prefetched f32 -> bf16 A-frags
        bf16x8 a[2];
        #pragma unroll
        for (int kc = 0; kc < 2; kc++) {
            union { bf16x8 v; unsigned u[4]; } u;
            f32x4 lo4 = pf[kc][0], hi4 = pf[kc][1];
            u.u[0] = pkbf(__float_as_uint(lo4.y), __float_as_uint(lo4.x));
            u.u[1] = pkbf(__float_as_uint(lo4.w), __float_as_uint(lo4.z));
            u.u[2] = pkbf(__float_as_uint(hi4.y), __float_as_uint(hi4.x));
            u.u[3] = pkbf(__float_as_uint(hi4.w), __float_as_uint(hi4.z));
            a[kc] = u.v;
        }
        #pragma unroll
        for (int qh = 0; qh < 4; qh++) {
            f32x4 acc = (f32x4){0.f, 0.f, 0.f, 0.f};
            acc = __builtin_amdgcn_mfma_f32_16x16x32_bf16(a[0], bq[qh][0], acc, 0,0,0);
            acc = __builtin_amdgcn_mfma_f32_16x16x32_bf16(a[1], bq[qh][1], acc, 0,0,0);
            unsigned k0 = key2(pkbf(__float_as_uint(acc.y), __float_as_uint(acc.x)));
            unsigned k1 = key2(pkbf(__float_as_uint(acc.w), __float_as_uint(acc.z)));
            uint2 kk; kk.x = k0; kk.y = k1;
            *(uint2*)&sc[qh*16 + fr][wv*16 + 4*fc] = kk;
        }
        __syncthreads();
        {   // prefetch next tile (wraps harmlessly on last)
            const float* p = &kbase[(size_t)(((mt+128)&(M_-1)) + wv*16 + fr)*HD + 8*fc];
            pf[0][0] = *(const f32x4*)p;      pf[0][1] = *(const f32x4*)(p+4);
            pf[1][0] = *(const f32x4*)(p+32); pf[1][1] = *(const f32x4*)(p+36);
        }
        // load my 16 keys into registers (one shot)
        int key[16];
        {
            const uint4* sp = (const uint4*)&sc[ql][lg << 4];
            uint4 w0 = sp[0], w1 = sp[1];
            key[0]=(int)(w0.x&0xFFFFu); key[1]=(int)(w0.x>>16);
            key[2]=(int)(w0.y&0xFFFFu); key[3]=(int)(w0.y>>16);
            key[4]=(int)(w0.z&0xFFFFu); key[5]=(int)(w0.z>>16);
            key[6]=(int)(w0.w&0xFFFFu); key[7]=(int)(w0.w>>16);
            key[8]=(int)(w1.x&0xFFFFu); key[9]=(int)(w1.x>>16);
            key[10]=(int)(w1.y&0xFFFFu); key[11]=(int)(w1.y>>16);
            key[12]=(int)(w1.z&0xFFFFu); key[13]=(int)(w1.z>>16);
            key[14]=(int)(w1.w&0xFFFFu); key[15]=(int)(w1.w>>16);
        }
        // register-resident collective top-NCAND merge (8 lanes / query)
        while (true) {
            // tree argmax over my 16 keys (depth-4 critical path, static idx)
            int tv8[8], tx8[8];
            #pragma unroll
            for (int p = 0; p < 8; p++) {
                bool g = key[2*p] >= key[2*p+1];
                tv8[p] = g ? key[2*p] : key[2*p+1];
                tx8[p] = g ? 2*p : 2*p+1;
            }
            #pragma unroll
            for (int p = 0; p < 4; p++) {
                bool g = tv8[p] >= tv8[p+4];
                tv8[p] = g ? tv8[p] : tv8[p+4];
                tx8[p] = g ? tx8[p] : tx8[p+4];
            }
            #pragma unroll
            for (int p = 0; p < 2; p++) {
                bool g = tv8[p] >= tv8[p+2];
                tv8[p] = g ? tv8[p] : tv8[p+2];
                tx8[p] = g ? tx8[p] : tx8[p+2];
            }
            bool gT = tv8[0] >= tv8[1];
            int mv = gT ? tv8[0] : tv8[1];
            int mloc = gT ? tx8[0] : tx8[1];
            int mi = (lg << 4) | mloc;
            // 8-lane argmax butterfly via DPP (full-rate VALU)
            { int ov=dppmov<0x141>(mv), oi=dppmov<0x141>(mi);
              if (ov>mv || (ov==mv && oi<mi)) { mv=ov; mi=oi; } }
            { int ov=dppmov<0x4E>(mv),  oi=dppmov<0x4E>(mi);
              if (ov>mv || (ov==mv && oi<mi)) { mv=ov; mi=oi; } }
            { int ov=dppmov<0xB1>(mv),  oi=dppmov<0xB1>(mi);
              if (ov>mv || (ov==mv && oi<mi)) { mv=ov; mi=oi; } }
            if (mv <= rmin) break;
            // sorted-desc insert into register list; prev rank via DPP row_shr:1
            int ov[CPL], oi[CPL];
            #pragma unroll
            for (int s = 0; s < CPL; s++) { ov[s] = ckey[s]; oi[s] = cidx[s]; }
            int pk = dppmov<0x111>(ckey[CPL-1]);
            int pj = dppmov<0x111>(cidx[CPL-1]);
            int pv = (lg==0) ? 0x10000 : pk;
            int pi = (lg==0) ? 0       : pj;
            int gidx = mt + mi;
            #pragma unroll
            for (int s = 0; s < CPL; s++) {
                int prev_v = s ? ov[s-1] : pv;
                int prev_i = s ? oi[s-1] : pi;
                bool gc = ov[s] > mv;
                bool gp = prev_v > mv;
                ckey[s] = gc ? ov[s] : (gp ? mv   : prev_v);
                cidx[s] = gc ? oi[s] : (gp ? gidx : prev_i);
            }
            // rmin = rank-39 value = min over 8 lanes of ckey[CPL-1]
            // (3-step DPP min butterfly, full-rate VALU; replaces ds_bpermute)
            {
                int rm = ckey[CPL-1];
                { int o = dppmov<0x141>(rm); rm = o < rm ? o : rm; }
                { int o = dppmov<0x4E>(rm);  rm = o < rm ? o : rm; }
                { int o = dppmov<0xB1>(rm);  rm = o < rm ? o : rm; }
                rmin = rm;
            }
            // owner clears extracted key (static-indexed)
            if ((mi >> 4) == lg) {
                int loc = mi & 15;
                #pragma unroll
                for (int t = 0; t < 16; t++) if (t == loc) key[t] = 0;
            }
        }
        __syncthreads();
    }

    // ---- exact f32 rescore of my CPL candidates ----
    float rsv[CPL]; int rsi[CPL];
    #pragma unroll
    for (int s2 = 0; s2 < CPL; s2++) {
        int idx = cidx[s2];
        const float* kr = &kbase[(size_t)idx * HD];
        float accr = 0.f;
        #pragma unroll
        for (int j = 0; j < 64; j += 4) {
            f32x4 kv = *(const f32x4*)&kr[j];
            f32x4 qv = *(const f32x4*)&qs[ql][j];
            accr += qv.x*kv.x + qv.y*kv.y + qv.z*kv.z + qv.w*kv.w;
        }
        rsv[s2] = accr; rsi[s2] = idx;
    }
    // ---- exact top-32 of 40 by extract-max (DPP reduce) ----
    const int qgb = bh*S_ + qt*64;
    float* tVo = &topV[(size_t)(qgb + ql)*32];
    int*   tIo = &topI[(size_t)(qgb + ql)*32];
    #pragma unroll 1
    for (int it = 0; it < 32; it++) {
        float mv = rsv[0]; int ms = 0;
        #pragma unroll
        for (int s2 = 1; s2 < CPL; s2++) if (rsv[s2] > mv) { mv = rsv[s2]; ms = s2; }
        int owner = (lg << 3) | ms;
        { float ovf=__int_as_float(dppmov<0x141>(__float_as_int(mv))); int oo=dppmov<0x141>(owner);
          if (ovf>mv || (ovf==mv && oo<owner)) { mv=ovf; owner=oo; } }
        { float ovf=__int_as_float(dppmov<0x4E>(__float_as_int(mv)));  int oo=dppmov<0x4E>(owner);
          if (ovf>mv || (ovf==mv && oo<owner)) { mv=ovf; owner=oo; } }
        { float ovf=__int_as_float(dppmov<0xB1>(__float_as_int(mv)));  int oo=dppmov<0xB1>(owner);
          if (ovf>mv || (ovf==mv && oo<owner)) { mv=ovf; owner=oo; } }
        if ((owner >> 3) == lg) {
            int ms2 = owner & 7;
            int idx = rsi[0];
            #pragma unroll
            for (int s2 = 1; s2 < CPL; s2++) if (ms2 == s2) idx = rsi[s2];
            #pragma unroll
            for (int s2 = 0; s2 < CPL; s2++) if (ms2 == s2) rsv[s2] = -INFINITY;
            tVo[it] = mv; tIo[it] = idx;
        }
    }
}

// ---------------- K5: fused local-causal + memory attention ----------------
__global__ __launch_bounds__(256) void attn_fused(
    const float* __restrict__ q, const float* __restrict__ k, const float* __restrict__ v,
    const float* __restrict__ topV, const int* __restrict__ topI,
    const float* __restrict__ memv, float* __restrict__ attn)
{
    __shared__ float Ks[64][68];
    __shared__ float Vs[64][68];
    __shared__ float Qs[32][68];
    __shared__ float pt[32][68];
    const int tid = threadIdx.x;
    const int qt = blockIdx.x, bh = blockIdx.y;
    const float* qbase = q + ((size_t)bh*S_ + qt*32)*HD;
    {
        int fi = tid; int r = fi>>4, c = (fi&15)<<2;
        float4 t4 = *(const float4*)&qbase[(size_t)r*HD + c];
        t4.x*=SCALE; t4.y*=SCALE; t4.z*=SCALE; t4.w*=SCALE;
        *(float4*)&Qs[r][c] = t4;
        fi = tid+256; r = fi>>4; c = (fi&15)<<2;
        t4 = *(const float4*)&qbase[(size_t)r*HD + c];
        t4.x*=SCALE; t4.y*=SCALE; t4.z*=SCALE; t4.w*=SCALE;
        *(float4*)&Qs[r][c] = t4;
    }
    __syncthreads();
    const int ql = tid>>3, lg = tid&7;
    const int dd0 = lg<<3;
    float qreg[64];
    #pragma unroll
    for (int j=0;j<64;j+=4) *(float4*)&qreg[j] = *(const float4*)&Qs[ql][j];
    const int qpos = qt*32 + ql;
    const size_t qg = (size_t)bh*S_ + qpos;

    float m = -INFINITY, l = 0.f;
    float acc[8] = {0,0,0,0,0,0,0,0};
    const float* tvp = &topV[qg*32];
    const int*   tip = &topI[qg*32];
    #pragma unroll 8
    for (int j=0;j<32;j++) m = fmaxf(m, tvp[j]*SCALE);
    #pragma unroll 4
    for (int j=0;j<32;j++) {
        float p = __expf(tvp[j]*SCALE - m);
        l += p;
        const float* mvr = &memv[((size_t)bh*M_ + tip[j])*HD + dd0];
        float4 a  = *(const float4*)&mvr[0];
        float4 b2 = *(const float4*)&mvr[4];
        acc[0]+=p*a.x;  acc[1]+=p*a.y;  acc[2]+=p*a.z;  acc[3]+=p*a.w;
        acc[4]+=p*b2.x; acc[5]+=p*b2.y; acc[6]+=p*b2.z; acc[7]+=p*b2.w;
    }
    const int ntiles = (qt*32 + 31)/64 + 1;
    const float* kb2 = k + ((size_t)bh*S_)*HD;
    const float* vb2 = v + ((size_t)bh*S_)*HD;
    for (int kt=0; kt<ntiles; kt++) {
        __syncthreads();
        for (int fi=tid; fi<1024; fi+=256) {
            int r = fi>>4, c = (fi&15)<<2;
            *(float4*)&Ks[r][c] = *(const float4*)&kb2[(size_t)(kt*64+r)*HD + c];
            *(float4*)&Vs[r][c] = *(const float4*)&vb2[(size_t)(kt*64+r)*HD + c];
        }
        __syncthreads();
        float s8[8];
        #pragma unroll
        for (int rr=0; rr<8; rr++) {
            int row = lg + (rr<<3);
            float acc2 = 0.f;
            #pragma unroll
            for (int j=0;j<64;j+=4) {
                float4 kv = *(const float4*)&Ks[row][j];
                acc2 += qreg[j]*kv.x + qreg[j+1]*kv.y + qreg[j+2]*kv.z + qreg[j+3]*kv.w;
            }
            int kpos = kt*64 + row;
            s8[rr] = (kpos <= qpos) ? acc2 : -INFINITY;
        }
        float tmax = s8[0];
        #pragma unroll
        for (int rr=1; rr<8; rr++) tmax = fmaxf(tmax, s8[rr]);
        #pragma unroll
        for (int off=1; off<8; off<<=1) tmax = fmaxf(tmax, __shfl_xor(tmax, off));
        float mnew = fmaxf(m, tmax);
        float f = __expf(m - mnew);
        l *= f;
        #pragma unroll
        for (int i=0;i<8;i++) acc[i] *= f;
        float psum = 0.f;
        #pragma unroll
        for (int rr=0; rr<8; rr++) {
            float p = __expf(s8[rr] - mnew);
            psum += p;
            pt[ql][lg + (rr<<3)] = p;
        }
        #pragma unroll
        for (int off=1; off<8; off<<=1) psum += __shfl_xor(psum, off);
        l += psum; m = mnew;
        #pragma unroll 8
        for (int r=0; r<64; r++) {
            float p = pt[ql][r];
            float4 a  = *(const float4*)&Vs[r][dd0];
            float4 b2 = *(const float4*)&Vs[r][dd0+4];
            acc[0]+=p*a.x;  acc[1]+=p*a.y;  acc[2]+=p*a.z;  acc[3]+=p*a.w;
            acc[4]+=p*b2.x; acc[5]+=p*b2.y; acc[6]+=p*b2.z; acc[7]+=p*b2.w;
        }
    }
    float inv = 1.0f / l;
    const int b = bh>>4, h = bh&15;
    float4 o;
    o.x=acc[0]*inv; o.y=acc[1]*inv; o.z=acc[2]*inv; o.w=acc[3]*inv;
    *(float4*)&attn[((size_t)(b*S_)+qpos)*HDIM + h*HD + dd0] = o;
    o.x=acc[4]*inv; o.y=acc[5]*inv; o.z=acc[6]*inv; o.w=acc[7]*inv;
    *(float4*)&attn[((size_t)(b*S_)+qpos)*HDIM + h*HD + dd0 + 4] = o;
}

extern "C" void kernel_launch(void* const* d_in, const int* in_sizes, int n_in,
                              void* d_out, int out_size, void* d_ws, size_t ws_size,
                              hipStream_t stream)
{
    const float* hs   = (const float*)d_in[0];
    const float* cosb = (const float*)d_in[1];
    const float* sinb = (const float*)d_in[2];
    const float* memk = (const float*)d_in[3];
    const float* memv = (const float*)d_in[4];
    const float* Wq = (const float*)d_in[5];
    const float* bq = (const float*)d_in[6];
    const float* Wk = (const float*)d_in[7];
    const float* bk = (const float*)d_in[8];
    const float* Wv = (const float*)d_in[9];
    const float* bv = (const float*)d_in[10];
    const float* Wo = (const float*)d_in[11];
    float* out = (float*)d_out;
    float* ws = (float*)d_ws;
    float* qw = ws;                    // 1M floats
    float* kw = ws + 1048576;          // 1M
    float* vw = ws + 2097152;          // 1M
    float* tV = ws + 3145728;          // 512K
    int*   tI = (int*)(ws + 3670016);  // 512K
    float* ao = ws + 4194304;          // 1M

    qkv_gemm<<<dim3(16,16,3),256,0,stream>>>(hs, Wq,bq,Wk,bk,Wv,bv, qw,kw,vw);
    rope_kernel<<<4096,256,0,stream>>>(qw,kw,cosb,sinb);
    sim_topk_mfma<<<256,512,0,stream>>>(qw, memk, tV, tI);
    attn_fused<<<dim3(16,32),256,0,stream>>>(qw,kw,vw, tV,tI, memv, ao);
    out_gemm<<<dim3(16,16),256,0,stream>>>(ao, Wo, out);
}

// Round 10
// 521.070 us; speedup vs baseline: 2.5133x; 1.3241x over previous
//
#include <hip/hip_runtime.h>
#include <cmath>

#define B_ 2
#define S_ 512
#define D_ 1024
#define H_ 16
#define HD 64
#define M_ 8192
#define HDIM 1024
#define SCALE 0.125f
#define LCAP 16    // per-lane private candidates; 8 lanes/query -> top-128 screen

using bf16x8 = __attribute__((ext_vector_type(8))) short;
using f32x4  = __attribute__((ext_vector_type(4))) float;

// pack two f32 (hi,lo) -> one u32 holding [bf16(lo) | bf16(hi)<<16] (truncation)
__device__ inline unsigned pkbf(unsigned hi, unsigned lo) {
    return __builtin_amdgcn_perm(hi, lo, 0x07060302u);
}
// monotone u16 sort keys for 2 packed bf16 (order-preserving for floats)
__device__ inline unsigned key2(unsigned u) {
    unsigned m = u & 0x80008000u;
    return u ^ (m - (m >> 15)) ^ 0x80008000u;
}

// DPP lane move (full-rate VALU). 0x141=row_half_mirror (i^7 within 8),
// 0x4E=quad_perm xor2, 0xB1=quad_perm xor1
template<int CTRL>
__device__ inline int dppmov(int x) {
    return __builtin_amdgcn_update_dpp(0, x, CTRL, 0xF, 0xF, true);
}

// ---------------- K1: QKV projection GEMM (64x64 tile, f32) ----------------
__global__ __launch_bounds__(256) void qkv_gemm(
    const float* __restrict__ A,
    const float* __restrict__ Wq, const float* __restrict__ bq,
    const float* __restrict__ Wk, const float* __restrict__ bk,
    const float* __restrict__ Wv, const float* __restrict__ bv,
    float* __restrict__ qo, float* __restrict__ ko, float* __restrict__ vo)
{
    const int which = blockIdx.z;
    const float* W    = (which==0)?Wq:((which==1)?Wk:Wv);
    const float* bias = (which==0)?bq:((which==1)?bk:bv);
    float* out        = (which==0)?qo:((which==1)?ko:vo);
    const int rb = blockIdx.y*64, cb = blockIdx.x*64;
    __shared__ float As[16][68];
    __shared__ float Bs[16][68];
    const int tid = threadIdx.x;
    const int ty = tid>>4, tx = tid&15;
    const int ar = tid>>2, ac4 = (tid&3)<<2;
    const int bkr = tid>>4, bc4 = (tid&15)<<2;
    float acc[4][4] = {};
    for (int kb=0; kb<D_; kb+=16) {
        float4 av  = *(const float4*)&A[(size_t)(rb+ar)*D_ + kb + ac4];
        float4 bvv = *(const float4*)&W[(size_t)(kb+bkr)*HDIM + cb + bc4];
        __syncthreads();
        As[ac4+0][ar]=av.x; As[ac4+1][ar]=av.y; As[ac4+2][ar]=av.z; As[ac4+3][ar]=av.w;
        *(float4*)&Bs[bkr][bc4] = bvv;
        __syncthreads();
        #pragma unroll
        for (int kk=0; kk<16; kk++) {
            float a[4], b[4];
            *(float4*)a = *(const float4*)&As[kk][ty<<2];
            *(float4*)b = *(const float4*)&Bs[kk][tx<<2];
            #pragma unroll
            for (int i=0;i<4;i++)
                #pragma unroll
                for (int j=0;j<4;j++) acc[i][j] += a[i]*b[j];
        }
    }
    const int c0 = cb + (tx<<2);
    float4 bb = *(const float4*)&bias[c0];
    const int h = c0>>6, dd = c0&63;
    #pragma unroll
    for (int i=0;i<4;i++) {
        int n = rb + (ty<<2) + i;
        int b = n>>9, s = n&511;
        float4 r;
        r.x = acc[i][0]+bb.x; r.y = acc[i][1]+bb.y;
        r.z = acc[i][2]+bb.z; r.w = acc[i][3]+bb.w;
        *(float4*)&out[((size_t)(b*H_+h)*S_ + s)*HD + dd] = r;
    }
}

// ---------------- K6: output projection GEMM ----------------
__global__ __launch_bounds__(256) void out_gemm(
    const float* __restrict__ A, const float* __restrict__ W, float* __restrict__ out)
{
    const int rb = blockIdx.y*64, cb = blockIdx.x*64;
    __shared__ float As[16][68];
    __shared__ float Bs[16][68];
    const int tid = threadIdx.x;
    const int ty = tid>>4, tx = tid&15;
    const int ar = tid>>2, ac4 = (tid&3)<<2;
    const int bkr = tid>>4, bc4 = (tid&15)<<2;
    float acc[4][4] = {};
    for (int kb=0; kb<HDIM; kb+=16) {
        float4 av  = *(const float4*)&A[(size_t)(rb+ar)*HDIM + kb + ac4];
        float4 bvv = *(const float4*)&W[(size_t)(kb+bkr)*D_ + cb + bc4];
        __syncthreads();
        As[ac4+0][ar]=av.x; As[ac4+1][ar]=av.y; As[ac4+2][ar]=av.z; As[ac4+3][ar]=av.w;
        *(float4*)&Bs[bkr][bc4] = bvv;
        __syncthreads();
        #pragma unroll
        for (int kk=0; kk<16; kk++) {
            float a[4], b[4];
            *(float4*)a = *(const float4*)&As[kk][ty<<2];
            *(float4*)b = *(const float4*)&Bs[kk][tx<<2];
            #pragma unroll
            for (int i=0;i<4;i++)
                #pragma unroll
                for (int j=0;j<4;j++) acc[i][j] += a[i]*b[j];
        }
    }
    const int c0 = cb + (tx<<2);
    #pragma unroll
    for (int i=0;i<4;i++) {
        int n = rb + (ty<<2) + i;
        float4 r;
        r.x=acc[i][0]; r.y=acc[i][1]; r.z=acc[i][2]; r.w=acc[i][3];
        *(float4*)&out[(size_t)n*D_ + c0] = r;
    }
}

// ---------------- K2: RoPE in-place on q,k ----------------
__global__ __launch_bounds__(256) void rope_kernel(
    float* __restrict__ q, float* __restrict__ k,
    const float* __restrict__ cosb, const float* __restrict__ sinb)
{
    int t = blockIdx.x*256 + threadIdx.x;
    int pair = t & 31;
    int s    = (t>>5) & 511;
    int bh   = (t>>14) & 31;
    float* x = (t>>19) ? k : q;
    float* xb = x + ((size_t)(bh*S_ + s))*HD;
    float c  = cosb[s*HD + pair];
    float sn = sinb[s*HD + pair];
    float x1 = xb[pair], x2 = xb[pair+32];
    xb[pair]    = x1*c - x2*sn;
    xb[pair+32] = x2*c + x1*sn;
}

// ---------------- K3: MFMA sim + per-lane private top-16 screen ------------
// 512 thr (8 waves), 64 queries x full M. Screen: each lane of an 8-lane
// query group keeps a PRIVATE sorted top-16 of its 1024-candidate stripe as
// packed u32 (key16<<16 | m-idx), maintained with a branch-free min/max
// insertion ladder (2 VALU/slot). No cross-lane ops, no divergence in the
// main loop. End: exact f32 rescore of the 128 screened candidates, exact
// top-32 via 8-lane DPP argmax.
__global__ __launch_bounds__(512) void sim_topk_mfma(
    const float* __restrict__ q, const float* __restrict__ memk,
    float* __restrict__ topV, int* __restrict__ topI)
{
    __shared__ unsigned short sc[64][136];        // bf16 sort-keys per (q, m); 16B-aligned rows
    __shared__ __align__(16) float qs[64][64];    // f32 q tile (for rescore)
    const int tid = threadIdx.x;
    // XCD-aware swizzle: 8 consecutive-on-XCD blocks share one bh panel
    int id = blockIdx.x;                 // 0..255
    int virt = (id & 7)*32 + (id >> 3);
    const int bh = virt >> 3, qt = virt & 7;
    const float* qbase = q + ((size_t)bh*S_ + qt*64)*HD;
    const float* kbase = memk + (size_t)bh*M_*HD;

    for (int i = tid; i < 64*16; i += 512) {      // stage q f32 (64x64)
        int r = i >> 4, c = (i & 15) << 2;
        *(f32x4*)&qs[r][c] = *(const f32x4*)&qbase[(size_t)r*HD + c];
    }
    __syncthreads();

    const int lane = tid & 63;
    const int wv = tid >> 6;                  // wave 0..7 -> m-subtile
    const int fr = lane & 15, fc = lane >> 4; // frag row / k-chunk

    // B-fragments: q[qh*16+fr][32*kc + 8*fc + j], truncated to bf16
    bf16x8 bq[4][2];
    #pragma unroll
    for (int qh = 0; qh < 4; qh++)
        #pragma unroll
        for (int kc = 0; kc < 2; kc++) {
            const float* p = &qs[qh*16 + fr][kc*32 + 8*fc];
            union { bf16x8 v; unsigned u[4]; } u;
            #pragma unroll
            for (int jj = 0; jj < 4; jj++)
                u.u[jj] = pkbf(__float_as_uint(p[2*jj+1]), __float_as_uint(p[2*jj]));
            bq[qh][kc] = u.v;
        }

    const int ql = tid >> 3, lg = tid & 7;
    // private sorted-desc top-LCAP, packed (key<<16)|idx, sentinel 0
    unsigned xs[LCAP];
    #pragma unroll
    for (int s = 0; s < LCAP; s++) xs[s] = 0u;

    f32x4 pf[2][2];
    {   // preload tile 0 A-fragments (f32)
        const float* p = &kbase[(size_t)(wv*16 + fr)*HD + 8*fc];
        pf[0][0] = *(const f32x4*)p;      pf[0][1] = *(const f32x4*)(p+4);
        pf[1][0] = *(const f32x4*)(p+32); pf[1][1] = *(const f32x4*)(p+36);
    }

    for (int mt = 0; mt < M_; mt += 128) {
        // convert prefetched f32 -> bf16 A-frags
        bf16x8 a[2];
        #pragma unroll
        for (int kc = 0; kc < 2; kc++) {
            union { bf16x8 v; unsigned u[4]; } u;
            f32x4 lo4 = pf[kc][0], hi4 = pf[kc][1];
            u.u[0] = pkbf(__float_as_uint(lo4.y), __float_as_uint(lo4.x));
            u.u[1] = pkbf(__float_as_uint(lo4.w), __float_as_uint(lo4.z));
            u.u[2] = pkbf(__float_as_uint(hi4.y), __float_as_uint(hi4.x));
            u.u[3] = pkbf(__float_as_uint(hi4.w), __float_as_uint(hi4.z));
            a[kc] = u.v;
        }
        #pragma unroll
        for (int qh = 0; qh < 4; qh++) {
            f32x4 acc = (f32x4){0.f, 0.f, 0.f, 0.f};
            acc = __builtin_amdgcn_mfma_f32_16x16x32_bf16(a[0], bq[qh][0], acc, 0,0,0);
            acc = __builtin_amdgcn_mfma_f32_16x16x32_bf16(a[1], bq[qh][1], acc, 0,0,0);
            unsigned k0 = key2(pkbf(__float_as_uint(acc.y), __float_as_uint(acc.x)));
            unsigned k1 = key2(pkbf(__float_as_uint(acc.w), __float_as_uint(acc.z)));
            uint2 kk; kk.x = k0; kk.y = k1;
            *(uint2*)&sc[qh*16 + fr][wv*16 + 4*fc] = kk;
        }
        __syncthreads();
        {   // prefetch next tile (wraps harmlessly on last)
            const float* p = &kbase[(size_t)(((mt+128)&(M_-1)) + wv*16 + fr)*HD + 8*fc];
            pf[0][0] = *(const f32x4*)p;      pf[0][1] = *(const f32x4*)(p+4);
            pf[1][0] = *(const f32x4*)(p+32); pf[1][1] = *(const f32x4*)(p+36);
        }
        // load my 16 keys (2 x b128) and run branch-free ladder inserts
        {
            const uint4* sp = (const uint4*)&sc[ql][lg << 4];
            uint4 w0v = sp[0], w1v = sp[1];
            unsigned wbuf[8] = {w0v.x, w0v.y, w0v.z, w0v.w,
                                w1v.x, w1v.y, w1v.z, w1v.w};
            const unsigned ibase = (unsigned)(mt + (lg << 4));
            #pragma unroll
            for (int p = 0; p < 8; p++) {
                unsigned w = wbuf[p];
                unsigned ve = (w << 16) | (ibase + 2*p);          // even key
                unsigned vo = (w & 0xFFFF0000u) | (ibase + 2*p + 1); // odd key
                #pragma unroll
                for (int s = 0; s < LCAP; s++) {
                    unsigned mx = xs[s] > ve ? xs[s] : ve;
                    unsigned mn = xs[s] > ve ? ve : xs[s];
                    xs[s] = mx; ve = mn;
                }
                #pragma unroll
                for (int s = 0; s < LCAP; s++) {
                    unsigned mx = xs[s] > vo ? xs[s] : vo;
                    unsigned mn = xs[s] > vo ? vo : xs[s];
                    xs[s] = mx; vo = mn;
                }
            }
        }
        __syncthreads();
    }

    // ---- exact f32 rescore of my LCAP candidates ----
    float rsv[LCAP]; int rsi[LCAP];
    #pragma unroll
    for (int s2 = 0; s2 < LCAP; s2++) {
        int idx = (int)(xs[s2] & 0xFFFFu);
        const float* kr = &kbase[(size_t)idx * HD];
        float accr = 0.f;
        #pragma unroll
        for (int j = 0; j < 64; j += 4) {
            f32x4 kv = *(const f32x4*)&kr[j];
            f32x4 qv = *(const f32x4*)&qs[ql][j];
            accr += qv.x*kv.x + qv.y*kv.y + qv.z*kv.z + qv.w*kv.w;
        }
        rsv[s2] = accr; rsi[s2] = idx;
    }
    // ---- exact top-32 of 128 by extract-max (DPP 8-lane argmax) ----
    const int qgb = bh*S_ + qt*64;
    float* tVo = &topV[(size_t)(qgb + ql)*32];
    int*   tIo = &topI[(size_t)(qgb + ql)*32];
    #pragma unroll 1
    for (int it = 0; it < 32; it++) {
        float mv = rsv[0]; int ms = 0;
        #pragma unroll
        for (int s2 = 1; s2 < LCAP; s2++) if (rsv[s2] > mv) { mv = rsv[s2]; ms = s2; }
        int owner = (lg << 4) | ms;
        { float ovf=__int_as_float(dppmov<0x141>(__float_as_int(mv))); int oo=dppmov<0x141>(owner);
          if (ovf>mv || (ovf==mv && oo<owner)) { mv=ovf; owner=oo; } }
        { float ovf=__int_as_float(dppmov<0x4E>(__float_as_int(mv)));  int oo=dppmov<0x4E>(owner);
          if (ovf>mv || (ovf==mv && oo<owner)) { mv=ovf; owner=oo; } }
        { float ovf=__int_as_float(dppmov<0xB1>(__float_as_int(mv)));  int oo=dppmov<0xB1>(owner);
          if (ovf>mv || (ovf==mv && oo<owner)) { mv=ovf; owner=oo; } }
        if ((owner >> 4) == lg) {
            int ms2 = owner & 15;
            int idx = rsi[0];
            #pragma unroll
            for (int s2 = 1; s2 < LCAP; s2++) if (ms2 == s2) idx = rsi[s2];
            #pragma unroll
            for (int s2 = 0; s2 < LCAP; s2++) if (ms2 == s2) rsv[s2] = -INFINITY;
            tVo[it] = mv; tIo[it] = idx;
        }
    }
}

// ---------------- K5: fused local-causal + memory attention ----------------
__global__ __launch_bounds__(256) void attn_fused(
    const float* __restrict__ q, const float* __restrict__ k, const float* __restrict__ v,
    const float* __restrict__ topV, const int* __restrict__ topI,
    const float* __restrict__ memv, float* __restrict__ attn)
{
    __shared__ float Ks[64][68];
    __shared__ float Vs[64][68];
    __shared__ float Qs[32][68];
    __shared__ float pt[32][68];
    const int tid = threadIdx.x;
    const int qt = blockIdx.x, bh = blockIdx.y;
    const float* qbase = q + ((size_t)bh*S_ + qt*32)*HD;
    {
        int fi = tid; int r = fi>>4, c = (fi&15)<<2;
        float4 t4 = *(const float4*)&qbase[(size_t)r*HD + c];
        t4.x*=SCALE; t4.y*=SCALE; t4.z*=SCALE; t4.w*=SCALE;
        *(float4*)&Qs[r][c] = t4;
        fi = tid+256; r = fi>>4; c = (fi&15)<<2;
        t4 = *(const float4*)&qbase[(size_t)r*HD + c];
        t4.x*=SCALE; t4.y*=SCALE; t4.z*=SCALE; t4.w*=SCALE;
        *(float4*)&Qs[r][c] = t4;
    }
    __syncthreads();
    const int ql = tid>>3, lg = tid&7;
    const int dd0 = lg<<3;
    float qreg[64];
    #pragma unroll
    for (int j=0;j<64;j+=4) *(float4*)&qreg[j] = *(const float4*)&Qs[ql][j];
    const int qpos = qt*32 + ql;
    const size_t qg = (size_t)bh*S_ + qpos;

    float m = -INFINITY, l = 0.f;
    float acc[8] = {0,0,0,0,0,0,0,0};
    const float* tvp = &topV[qg*32];
    const int*   tip = &topI[qg*32];
    #pragma unroll 8
    for (int j=0;j<32;j++) m = fmaxf(m, tvp[j]*SCALE);
    #pragma unroll 4
    for (int j=0;j<32;j++) {
        float p = __expf(tvp[j]*SCALE - m);
        l += p;
        const float* mvr = &memv[((size_t)bh*M_ + tip[j])*HD + dd0];
        float4 a  = *(const float4*)&mvr[0];
        float4 b2 = *(const float4*)&mvr[4];
        acc[0]+=p*a.x;  acc[1]+=p*a.y;  acc[2]+=p*a.z;  acc[3]+=p*a.w;
        acc[4]+=p*b2.x; acc[5]+=p*b2.y; acc[6]+=p*b2.z; acc[7]+=p*b2.w;
    }
    const int ntiles = (qt*32 + 31)/64 + 1;
    const float* kb2 = k + ((size_t)bh*S_)*HD;
    const float* vb2 = v + ((size_t)bh*S_)*HD;
    for (int kt=0; kt<ntiles; kt++) {
        __syncthreads();
        for (int fi=tid; fi<1024; fi+=256) {
            int r = fi>>4, c = (fi&15)<<2;
            *(float4*)&Ks[r][c] = *(const float4*)&kb2[(size_t)(kt*64+r)*HD + c];
            *(float4*)&Vs[r][c] = *(const float4*)&vb2[(size_t)(kt*64+r)*HD + c];
        }
        __syncthreads();
        float s8[8];
        #pragma unroll
        for (int rr=0; rr<8; rr++) {
            int row = lg + (rr<<3);
            float acc2 = 0.f;
            #pragma unroll
            for (int j=0;j<64;j+=4) {
                float4 kv = *(const float4*)&Ks[row][j];
                acc2 += qreg[j]*kv.x + qreg[j+1]*kv.y + qreg[j+2]*kv.z + qreg[j+3]*kv.w;
            }
            int kpos = kt*64 + row;
            s8[rr] = (kpos <= qpos) ? acc2 : -INFINITY;
        }
        float tmax = s8[0];
        #pragma unroll
        for (int rr=1; rr<8; rr++) tmax = fmaxf(tmax, s8[rr]);
        #pragma unroll
        for (int off=1; off<8; off<<=1) tmax = fmaxf(tmax, __shfl_xor(tmax, off));
        float mnew = fmaxf(m, tmax);
        float f = __expf(m - mnew);
        l *= f;
        #pragma unroll
        for (int i=0;i<8;i++) acc[i] *= f;
        float psum = 0.f;
        #pragma unroll
        for (int rr=0; rr<8; rr++) {
            float p = __expf(s8[rr] - mnew);
            psum += p;
            pt[ql][lg + (rr<<3)] = p;
        }
        #pragma unroll
        for (int off=1; off<8; off<<=1) psum += __shfl_xor(psum, off);
        l += psum; m = mnew;
        #pragma unroll 8
        for (int r=0; r<64; r++) {
            float p = pt[ql][r];
            float4 a  = *(const float4*)&Vs[r][dd0];
            float4 b2 = *(const float4*)&Vs[r][dd0+4];
            acc[0]+=p*a.x;  acc[1]+=p*a.y;  acc[2]+=p*a.z;  acc[3]+=p*a.w;
            acc[4]+=p*b2.x; acc[5]+=p*b2.y; acc[6]+=p*b2.z; acc[7]+=p*b2.w;
        }
    }
    float inv = 1.0f / l;
    const int b = bh>>4, h = bh&15;
    float4 o;
    o.x=acc[0]*inv; o.y=acc[1]*inv; o.z=acc[2]*inv; o.w=acc[3]*inv;
    *(float4*)&attn[((size_t)(b*S_)+qpos)*HDIM + h*HD + dd0] = o;
    o.x=acc[4]*inv; o.y=acc[5]*inv; o.z=acc[6]*inv; o.w=acc[7]*inv;
    *(float4*)&attn[((size_t)(b*S_)+qpos)*HDIM + h*HD + dd0 + 4] = o;
}

extern "C" void kernel_launch(void* const* d_in, const int* in_sizes, int n_in,
                              void* d_out, int out_size, void* d_ws, size_t ws_size,
                              hipStream_t stream)
{
    const float* hs   = (const float*)d_in[0];
    const float* cosb = (const float*)d_in[1];
    const float* sinb = (const float*)d_in[2];
    const float* memk = (const float*)d_in[3];
    const float* memv = (const float*)d_in[4];
    const float* Wq = (const float*)d_in[5];
    const float* bq = (const float*)d_in[6];
    const float* Wk = (const float*)d_in[7];
    const float* bk = (const float*)d_in[8];
    const float* Wv = (const float*)d_in[9];
    const float* bv = (const float*)d_in[10];
    const float* Wo = (const float*)d_in[11];
    float* out = (float*)d_out;
    float* ws = (float*)d_ws;
    float* qw = ws;                    // 1M floats
    float* kw = ws + 1048576;          // 1M
    float* vw = ws + 2097152;          // 1M
    float* tV = ws + 3145728;          // 512K
    int*   tI = (int*)(ws + 3670016);  // 512K
    float* ao = ws + 4194304;          // 1M

    qkv_gemm<<<dim3(16,16,3),256,0,stream>>>(hs, Wq,bq,Wk,bk,Wv,bv, qw,kw,vw);
    rope_kernel<<<4096,256,0,stream>>>(qw,kw,cosb,sinb);
    sim_topk_mfma<<<256,512,0,stream>>>(qw, memk, tV, tI);
    attn_fused<<<dim3(16,32),256,0,stream>>>(qw,kw,vw, tV,tI, memv, ao);
    out_gemm<<<dim3(16,16),256,0,stream>>>(ao, Wo, out);
}